// Round 3
// baseline (432.636 us; speedup 1.0000x reference)
//
#include <hip/hip_runtime.h>
#include <cstdint>
#include <cstddef>

typedef __attribute__((ext_vector_type(4))) float f32x4;
typedef __attribute__((ext_vector_type(8))) short s16x8;
typedef __attribute__((ext_vector_type(4))) short s16x4;

#define B_  2
#define T_  2048
#define C_  2048
#define H_  16
#define KV_ 4
#define D_  128
#define M_  4096   // B*T

static __device__ __forceinline__ float bf2f(ushort u){
  union { float f; uint32_t u; } x; x.u = ((uint32_t)u) << 16; return x.f;
}
static __device__ __forceinline__ ushort f2bf(float f){
  union { float f; uint32_t u; } x; x.f = f;
  uint32_t r = x.u + 0x7FFF + ((x.u >> 16) & 1);
  return (ushort)(r >> 16);
}

// ---------------- fp32 -> bf16 elementwise ----------------
__global__ void cvt_f32_bf16(const float* __restrict__ in, ushort* __restrict__ out, int n4){
  int idx = blockIdx.x * blockDim.x + threadIdx.x;
  int stride = gridDim.x * blockDim.x;
  for (int i = idx; i < n4; i += stride){
    float4 v = ((const float4*)in)[i];
    s16x4 o;
    o[0] = (short)f2bf(v.x); o[1] = (short)f2bf(v.y);
    o[2] = (short)f2bf(v.z); o[3] = (short)f2bf(v.w);
    ((s16x4*)out)[i] = o;
  }
}

// ---------------- fp32 [K][N] -> bf16 [N][K] transpose ----------------
__global__ void transpose_cvt(const float* __restrict__ W, ushort* __restrict__ Wt, int K, int N){
  __shared__ float tile[32][33];
  int n0 = blockIdx.x * 32, k0 = blockIdx.y * 32;
  int tx = threadIdx.x, ty = threadIdx.y;   // 32 x 8
  #pragma unroll
  for (int r = 0; r < 4; r++)
    tile[ty + 8*r][tx] = W[(size_t)(k0 + ty + 8*r) * N + n0 + tx];
  __syncthreads();
  #pragma unroll
  for (int r = 0; r < 4; r++)
    Wt[(size_t)(n0 + ty + 8*r) * K + k0 + tx] = f2bf(tile[tx][ty + 8*r]);
}

// ---------------- GEMM: C = A[M,K] * Bt[N,K]^T (bf16 in, fp32 acc) ----------------
// MODE 1: bf16 out scattered to [B,NH,T,D]
// MODE 2: bf16 out scattered to [B,NH,D,T] (V transposed)
// MODE 3: fp32 out row-major [M,N]
template<int MODE, int NH>
__global__ __launch_bounds__(256)
void gemm_bt(const ushort* __restrict__ A, const ushort* __restrict__ Bt,
             void* __restrict__ Cout, int N, int Kd){
  __shared__ __align__(16) ushort As[128 * 40];
  __shared__ __align__(16) ushort Bs[128 * 40];
  int tid = threadIdx.x;
  int w = tid >> 6, l = tid & 63;
  int l15 = l & 15, l4 = l >> 4;
  int rblk = blockIdx.y * 128, cblk = blockIdx.x * 128;
  int rw = (w >> 1) * 64, cw = (w & 1) * 64;

  int c0 = tid, c1 = tid + 256;
  const ushort* Ag0 = A  + (size_t)(rblk + (c0 >> 2)) * Kd + (c0 & 3) * 8;
  const ushort* Ag1 = A  + (size_t)(rblk + (c1 >> 2)) * Kd + (c1 & 3) * 8;
  const ushort* Bg0 = Bt + (size_t)(cblk + (c0 >> 2)) * Kd + (c0 & 3) * 8;
  const ushort* Bg1 = Bt + (size_t)(cblk + (c1 >> 2)) * Kd + (c1 & 3) * 8;
  ushort* As0 = As + (c0 >> 2) * 40 + (c0 & 3) * 8;
  ushort* As1 = As + (c1 >> 2) * 40 + (c1 & 3) * 8;
  ushort* Bs0 = Bs + (c0 >> 2) * 40 + (c0 & 3) * 8;
  ushort* Bs1 = Bs + (c1 >> 2) * 40 + (c1 & 3) * 8;

  f32x4 acc[4][4] = {};

  for (int k0 = 0; k0 < Kd; k0 += 32){
    *(s16x8*)As0 = *(const s16x8*)(Ag0 + k0);
    *(s16x8*)As1 = *(const s16x8*)(Ag1 + k0);
    *(s16x8*)Bs0 = *(const s16x8*)(Bg0 + k0);
    *(s16x8*)Bs1 = *(const s16x8*)(Bg1 + k0);
    __syncthreads();
    s16x8 af[4], bfv[4];
    #pragma unroll
    for (int m = 0; m < 4; m++)
      af[m] = *(const s16x8*)(As + (rw + 16*m + l15) * 40 + l4 * 8);
    #pragma unroll
    for (int n = 0; n < 4; n++)
      bfv[n] = *(const s16x8*)(Bs + (cw + 16*n + l15) * 40 + l4 * 8);
    #pragma unroll
    for (int m = 0; m < 4; m++)
      #pragma unroll
      for (int n = 0; n < 4; n++)
        acc[m][n] = __builtin_amdgcn_mfma_f32_16x16x32_bf16(af[m], bfv[n], acc[m][n], 0, 0, 0);
    __syncthreads();
  }

  #pragma unroll
  for (int m = 0; m < 4; m++){
    #pragma unroll
    for (int n = 0; n < 4; n++){
      #pragma unroll
      for (int j = 0; j < 4; j++){
        int row = rblk + rw + 16*m + l4*4 + j;
        int col = cblk + cw + 16*n + l15;
        float v = acc[m][n][j];
        if (MODE == 1){
          int t = row & (T_ - 1), b = row >> 11;
          int hh = col >> 7, d = col & 127;
          ((ushort*)Cout)[(((size_t)(b * NH + hh)) * T_ + t) * D_ + d] = f2bf(v);
        } else if (MODE == 2){
          int t = row & (T_ - 1), b = row >> 11;
          int hh = col >> 7, d = col & 127;
          ((ushort*)Cout)[(((size_t)(b * NH + hh)) * D_ + d) * T_ + t] = f2bf(v);
        } else {
          ((float*)Cout)[(size_t)row * N + col] = v;
        }
      }
    }
  }
}

// ---------------- RoPE in place on [B*NH, T, D] ----------------
__global__ void rope_inplace(ushort* __restrict__ X, float scale){
  int t = blockIdx.x;
  int bh = blockIdx.y;
  int d = threadIdx.x;    // 0..63
  ushort* row = X + ((size_t)bh * T_ + t) * D_;
  float q1 = bf2f(row[d]);
  float q2 = bf2f(row[d + 64]);
  float invf = exp2f(-(float)d * 0.2076205059304602f);  // log2(10000)/64
  float angle = (float)t * invf;
  float s, c;
  __sincosf(angle, &s, &c);
  row[d]      = f2bf((q1 * c - q2 * s) * scale);
  row[d + 64] = f2bf((q2 * c + q1 * s) * scale);
}

// ---------------- causal GQA flash attention ----------------
// Q [B,H,T,D] (pre-scaled by D^-0.5), K [B,KV,T,D], Vt [B,KV,D,T] -> O [B*T, H*D] bf16
__global__ __launch_bounds__(256)
void attn_kernel(const ushort* __restrict__ Q, const ushort* __restrict__ Kc,
                 const ushort* __restrict__ Vt, ushort* __restrict__ O){
  __shared__ __align__(16) ushort Ks[64 * 136];
  __shared__ __align__(16) ushort Vs[128 * 72];
  __shared__ __align__(16) ushort Ps[64 * 72];
  int qt = blockIdx.x;
  int bh = blockIdx.y;
  int b = bh >> 4, h = bh & 15, kvh = h >> 2;
  int tid = threadIdx.x, w = tid >> 6, l = tid & 63;
  int l15 = l & 15, l4 = l >> 4;
  int q0 = qt * 64;

  // Q fragments, register-resident across kv loop (wave w owns q rows q0+16w .. +16)
  s16x8 qf[4];
  const ushort* qbase = Q + (((size_t)(b * H_ + h)) * T_ + q0 + 16*w + l15) * D_;
  #pragma unroll
  for (int kk = 0; kk < 4; kk++)
    qf[kk] = *(const s16x8*)(qbase + kk * 32 + l4 * 8);

  f32x4 oacc[8] = {};
  float mrun[4] = {-1e30f, -1e30f, -1e30f, -1e30f};
  float lrun[4] = {0.f, 0.f, 0.f, 0.f};

  const ushort* kbase = Kc + ((size_t)(b * KV_ + kvh)) * T_ * D_;
  const ushort* vbase = Vt + ((size_t)(b * KV_ + kvh)) * D_ * T_;

  for (int jt = 0; jt <= qt; jt++){
    int k0 = jt * 64;
    #pragma unroll
    for (int i = 0; i < 4; i++){
      int c = tid + 256 * i;
      int r = c >> 4, cb = c & 15;
      *(s16x8*)(Ks + r * 136 + cb * 8) = *(const s16x8*)(kbase + (size_t)(k0 + r) * D_ + cb * 8);
      int dd = c >> 3, tb = c & 7;
      *(s16x8*)(Vs + dd * 72 + tb * 8) = *(const s16x8*)(vbase + (size_t)dd * T_ + k0 + tb * 8);
    }
    __syncthreads();

    // S = Q K^T  (rows: this wave's 16 q rows, cols: 64 k)
    f32x4 sacc[4] = {};
    #pragma unroll
    for (int kk = 0; kk < 4; kk++){
      #pragma unroll
      for (int n = 0; n < 4; n++){
        s16x8 kf = *(const s16x8*)(Ks + (16*n + l15) * 136 + kk * 32 + l4 * 8);
        sacc[n] = __builtin_amdgcn_mfma_f32_16x16x32_bf16(qf[kk], kf, sacc[n], 0, 0, 0);
      }
    }
    if (jt == qt){
      #pragma unroll
      for (int n = 0; n < 4; n++)
        #pragma unroll
        for (int j = 0; j < 4; j++){
          int qrow = 16*w + l4*4 + j;
          int kcol = 16*n + l15;
          if (kcol > qrow) sacc[n][j] = -1e30f;
        }
    }
    // online softmax
    float alpha[4];
    #pragma unroll
    for (int j = 0; j < 4; j++){
      float m = fmaxf(fmaxf(sacc[0][j], sacc[1][j]), fmaxf(sacc[2][j], sacc[3][j]));
      m = fmaxf(m, __shfl_xor(m, 1));
      m = fmaxf(m, __shfl_xor(m, 2));
      m = fmaxf(m, __shfl_xor(m, 4));
      m = fmaxf(m, __shfl_xor(m, 8));
      float mnew = fmaxf(mrun[j], m);
      alpha[j] = __expf(mrun[j] - mnew);
      mrun[j] = mnew;
    }
    float rs[4] = {0.f, 0.f, 0.f, 0.f};
    #pragma unroll
    for (int n = 0; n < 4; n++)
      #pragma unroll
      for (int j = 0; j < 4; j++){
        float p = __expf(sacc[n][j] - mrun[j]);
        rs[j] += p;
        Ps[(16*w + l4*4 + j) * 72 + 16*n + l15] = f2bf(p);
      }
    #pragma unroll
    for (int j = 0; j < 4; j++){
      float r = rs[j];
      r += __shfl_xor(r, 1); r += __shfl_xor(r, 2);
      r += __shfl_xor(r, 4); r += __shfl_xor(r, 8);
      lrun[j] = lrun[j] * alpha[j] + r;
    }
    #pragma unroll
    for (int n8 = 0; n8 < 8; n8++)
      #pragma unroll
      for (int j = 0; j < 4; j++)
        oacc[n8][j] *= alpha[j];
    // O += P V   (P is per-wave private in LDS; same-wave ds ordering suffices)
    #pragma unroll
    for (int kk = 0; kk < 2; kk++){
      s16x8 pf = *(const s16x8*)(Ps + (16*w + l15) * 72 + kk * 32 + l4 * 8);
      #pragma unroll
      for (int n8 = 0; n8 < 8; n8++){
        s16x8 vf = *(const s16x8*)(Vs + (16*n8 + l15) * 72 + kk * 32 + l4 * 8);
        oacc[n8] = __builtin_amdgcn_mfma_f32_16x16x32_bf16(pf, vf, oacc[n8], 0, 0, 0);
      }
    }
    __syncthreads();
  }

  #pragma unroll
  for (int n8 = 0; n8 < 8; n8++)
    #pragma unroll
    for (int j = 0; j < 4; j++){
      int t = q0 + 16*w + l4*4 + j;
      int dcol = 16*n8 + l15;
      float v = oacc[n8][j] / lrun[j];
      O[((size_t)(b * T_ + t)) * C_ + h * D_ + dcol] = f2bf(v);
    }
}

// ---------------- launch ----------------
extern "C" void kernel_launch(void* const* d_in, const int* in_sizes, int n_in,
                              void* d_out, int out_size, void* d_ws, size_t ws_size,
                              hipStream_t stream){
  const float* x  = (const float*)d_in[0];
  const float* Wq = (const float*)d_in[1];
  const float* Wk = (const float*)d_in[2];
  const float* Wv = (const float*)d_in[3];
  const float* Wo = (const float*)d_in[4];
  float* out = (float*)d_out;

  char* ws = (char*)d_ws;
  size_t off = 0;
  auto alloc = [&](size_t bytes)->void*{
    void* p = ws + off; off += (bytes + 255) & ~(size_t)255; return p;
  };
  ushort* xb  = (ushort*)alloc((size_t)M_ * C_ * 2);
  ushort* Wqt = (ushort*)alloc((size_t)2048 * 2048 * 2);
  ushort* Wkt = (ushort*)alloc((size_t)512 * 2048 * 2);
  ushort* Wvt = (ushort*)alloc((size_t)512 * 2048 * 2);
  ushort* Wot = (ushort*)alloc((size_t)2048 * 2048 * 2);
  ushort* Qb  = (ushort*)alloc((size_t)B_ * H_ * T_ * D_ * 2);
  ushort* Kb  = (ushort*)alloc((size_t)B_ * KV_ * T_ * D_ * 2);
  ushort* Vtb = (ushort*)alloc((size_t)B_ * KV_ * T_ * D_ * 2);
  ushort* Ob  = (ushort*)alloc((size_t)M_ * C_ * 2);

  cvt_f32_bf16<<<2048, 256, 0, stream>>>(x, xb, M_ * C_ / 4);
  transpose_cvt<<<dim3(64, 64), dim3(32, 8), 0, stream>>>(Wq, Wqt, 2048, 2048);
  transpose_cvt<<<dim3(16, 64), dim3(32, 8), 0, stream>>>(Wk, Wkt, 2048, 512);
  transpose_cvt<<<dim3(16, 64), dim3(32, 8), 0, stream>>>(Wv, Wvt, 2048, 512);
  transpose_cvt<<<dim3(64, 64), dim3(32, 8), 0, stream>>>(Wo, Wot, 2048, 2048);

  gemm_bt<1, H_ ><<<dim3(16, 32), 256, 0, stream>>>(xb, Wqt, Qb,  2048, 2048);
  gemm_bt<1, KV_><<<dim3(4, 32),  256, 0, stream>>>(xb, Wkt, Kb,  512,  2048);
  gemm_bt<2, KV_><<<dim3(4, 32),  256, 0, stream>>>(xb, Wvt, Vtb, 512,  2048);

  rope_inplace<<<dim3(T_, B_ * H_),  64, 0, stream>>>(Qb, 0.08838834764831845f);
  rope_inplace<<<dim3(T_, B_ * KV_), 64, 0, stream>>>(Kb, 1.0f);

  attn_kernel<<<dim3(T_ / 64, B_ * H_), 256, 0, stream>>>(Qb, Kb, Vtb, Ob);

  gemm_bt<3, 1><<<dim3(16, 32), 256, 0, stream>>>(Ob, Wot, out, 2048, 2048);
}

// Round 4
// 361.706 us; speedup vs baseline: 1.1961x; 1.1961x over previous
//
#include <hip/hip_runtime.h>
#include <cstdint>
#include <cstddef>

typedef __attribute__((ext_vector_type(4))) float f32x4;
typedef __attribute__((ext_vector_type(8))) short s16x8;
typedef __attribute__((ext_vector_type(4))) short s16x4;

#define B_  2
#define T_  2048
#define C_  2048
#define H_  16
#define KV_ 4
#define D_  128
#define M_  4096   // B*T

static __device__ __forceinline__ float bf2f(ushort u){
  union { float f; uint32_t u; } x; x.u = ((uint32_t)u) << 16; return x.f;
}
static __device__ __forceinline__ ushort f2bf(float f){
  union { float f; uint32_t u; } x; x.f = f;
  uint32_t r = x.u + 0x7FFF + ((x.u >> 16) & 1);
  return (ushort)(r >> 16);
}

// async global->LDS, 16B per lane; dest = wave-uniform base + lane*16
static __device__ __forceinline__ void gl_lds16(const ushort* g, ushort* s){
  __builtin_amdgcn_global_load_lds((const __attribute__((address_space(1))) void*)g,
                                   (__attribute__((address_space(3))) void*)s, 16, 0, 0);
}

// ---------------- fp32 -> bf16 elementwise ----------------
__global__ void cvt_f32_bf16(const float* __restrict__ in, ushort* __restrict__ out, int n4){
  int idx = blockIdx.x * blockDim.x + threadIdx.x;
  int stride = gridDim.x * blockDim.x;
  for (int i = idx; i < n4; i += stride){
    float4 v = ((const float4*)in)[i];
    s16x4 o;
    o[0] = (short)f2bf(v.x); o[1] = (short)f2bf(v.y);
    o[2] = (short)f2bf(v.z); o[3] = (short)f2bf(v.w);
    ((s16x4*)out)[i] = o;
  }
}

// ---------------- fp32 [K][N] -> bf16 [N][K] transpose ----------------
__global__ void transpose_cvt(const float* __restrict__ W, ushort* __restrict__ Wt, int K, int N){
  __shared__ float tile[32][33];
  int n0 = blockIdx.x * 32, k0 = blockIdx.y * 32;
  int tx = threadIdx.x, ty = threadIdx.y;   // 32 x 8
  #pragma unroll
  for (int r = 0; r < 4; r++)
    tile[ty + 8*r][tx] = W[(size_t)(k0 + ty + 8*r) * N + n0 + tx];
  __syncthreads();
  #pragma unroll
  for (int r = 0; r < 4; r++)
    Wt[(size_t)(n0 + ty + 8*r) * K + k0 + tx] = f2bf(tile[tx][ty + 8*r]);
}

// ---------------- GEMM (m97 structure): C = A[M,K] * Bt[N,K]^T ----------------
// MODE 1: bf16 out scattered to [B,NH,T,D]
// MODE 2: bf16 out scattered to [B,NH,D,T] (V transposed)
// MODE 3: fp32 out row-major [M,N]
template<int MODE, int NH>
__global__ __launch_bounds__(256)
void gemm_bt(const ushort* __restrict__ A, const ushort* __restrict__ Bt,
             void* __restrict__ Cout, int N, int Kd){
  __shared__ __align__(16) ushort As[128 * 32];   // linear, global_load_lds dest
  __shared__ __align__(16) ushort Bs[128 * 32];
  int tid = threadIdx.x;
  int w = tid >> 6, l = tid & 63;
  int l15 = l & 15, l4 = l >> 4;
  int rblk = blockIdx.y * 128, cblk = blockIdx.x * 128;
  int rw = (w >> 1) * 64, cw = (w & 1) * 64;

  // staging: chunk = 16 rows of 32 cols = 1024B, one wave-issue each; 8 chunks per tile
  int ch0 = w * 2, ch1 = w * 2 + 1;
  int srow0 = ch0 * 16 + (l >> 2), srow1 = ch1 * 16 + (l >> 2);
  int scol = (l & 3) * 8;
  const ushort* gA0 = A  + (size_t)(rblk + srow0) * Kd + scol;
  const ushort* gA1 = A  + (size_t)(rblk + srow1) * Kd + scol;
  const ushort* gB0 = Bt + (size_t)(cblk + srow0) * Kd + scol;
  const ushort* gB1 = Bt + (size_t)(cblk + srow1) * Kd + scol;
  ushort* lA0 = As + ch0 * 512;  ushort* lA1 = As + ch1 * 512;
  ushort* lB0 = Bs + ch0 * 512;  ushort* lB1 = Bs + ch1 * 512;

  f32x4 acc[4][4] = {};

  for (int k0 = 0; k0 < Kd; k0 += 32){
    gl_lds16(gA0 + k0, lA0);
    gl_lds16(gA1 + k0, lA1);
    gl_lds16(gB0 + k0, lB0);
    gl_lds16(gB1 + k0, lB1);
    __syncthreads();   // compiler emits vmcnt(0) drain before barrier
    s16x8 af[4], bfv[4];
    #pragma unroll
    for (int m = 0; m < 4; m++)
      af[m] = *(const s16x8*)(As + (rw + 16*m + l15) * 32 + l4 * 8);
    #pragma unroll
    for (int n = 0; n < 4; n++)
      bfv[n] = *(const s16x8*)(Bs + (cw + 16*n + l15) * 32 + l4 * 8);
    #pragma unroll
    for (int m = 0; m < 4; m++)
      #pragma unroll
      for (int n = 0; n < 4; n++)
        acc[m][n] = __builtin_amdgcn_mfma_f32_16x16x32_bf16(af[m], bfv[n], acc[m][n], 0, 0, 0);
    __syncthreads();
  }

  #pragma unroll
  for (int m = 0; m < 4; m++){
    #pragma unroll
    for (int n = 0; n < 4; n++){
      #pragma unroll
      for (int j = 0; j < 4; j++){
        int row = rblk + rw + 16*m + l4*4 + j;
        int col = cblk + cw + 16*n + l15;
        float v = acc[m][n][j];
        if (MODE == 1){
          int t = row & (T_ - 1), b = row >> 11;
          int hh = col >> 7, d = col & 127;
          ((ushort*)Cout)[(((size_t)(b * NH + hh)) * T_ + t) * D_ + d] = f2bf(v);
        } else if (MODE == 2){
          int t = row & (T_ - 1), b = row >> 11;
          int hh = col >> 7, d = col & 127;
          ((ushort*)Cout)[(((size_t)(b * NH + hh)) * D_ + d) * T_ + t] = f2bf(v);
        } else {
          ((float*)Cout)[(size_t)row * N + col] = v;
        }
      }
    }
  }
}

// ---------------- RoPE in place on [B*NH, T, D] ----------------
__global__ void rope_inplace(ushort* __restrict__ X, float scale){
  int t = blockIdx.x;
  int bh = blockIdx.y;
  int d = threadIdx.x;    // 0..63
  ushort* row = X + ((size_t)bh * T_ + t) * D_;
  float q1 = bf2f(row[d]);
  float q2 = bf2f(row[d + 64]);
  float invf = exp2f(-(float)d * 0.2076205059304602f);  // log2(10000)/64
  float angle = (float)t * invf;
  float s, c;
  __sincosf(angle, &s, &c);
  row[d]      = f2bf((q1 * c - q2 * s) * scale);
  row[d + 64] = f2bf((q2 * c + q1 * s) * scale);
}

// ---------------- causal GQA flash attention (v2: GQA-shared K/V) ----------------
// Block = (b, kvh, 32-row q tile) serving all 4 q-heads of the kv group.
// 8 waves: wave w -> head kvh*4 + (w>>1), q rows qt*32 + (w&1)*16 .. +16.
// Q pre-scaled by D^-0.5. K [B,KV,T,D], Vt [B,KV,D,T] -> O [B*T, H*D] bf16.
__global__ __launch_bounds__(512, 4)
void attn_kernel2(const ushort* __restrict__ Q, const ushort* __restrict__ Kc,
                  const ushort* __restrict__ Vt, ushort* __restrict__ O){
  __shared__ __align__(16) ushort Ks[64 * 136];      // 64 kv rows x 128 d (pad 8)
  __shared__ __align__(16) ushort Vs[128 * 72];      // 128 d x 64 t (pad 8)
  __shared__ __align__(16) ushort Ps[8 * 16 * 72];   // per-wave 16 x 64 (pad 8)
  int bid = blockIdx.x;
  int qt  = 63 - (bid >> 3);          // LPT: longest q-tiles dispatch first
  int sub = bid & 7;
  int b = sub >> 2, kvh = sub & 3;
  int tid = threadIdx.x, w = tid >> 6, l = tid & 63;
  int l15 = l & 15, l4 = l >> 4;
  int q0 = qt * 32;
  int hq = kvh * 4 + (w >> 1);
  int qrow0 = q0 + (w & 1) * 16;      // this wave's 16 q rows

  s16x8 qf[4];
  const ushort* qbase = Q + (((size_t)(b * H_ + hq)) * T_ + qrow0 + l15) * D_;
  #pragma unroll
  for (int kk = 0; kk < 4; kk++)
    qf[kk] = *(const s16x8*)(qbase + kk * 32 + l4 * 8);

  f32x4 oacc[8] = {};
  float mrun[4] = {-1e30f, -1e30f, -1e30f, -1e30f};
  float lrun[4] = {0.f, 0.f, 0.f, 0.f};
  ushort* Pw = Ps + w * 16 * 72;

  const ushort* kbase = Kc + ((size_t)(b * KV_ + kvh)) * T_ * D_;
  const ushort* vbase = Vt + ((size_t)(b * KV_ + kvh)) * D_ * T_;
  int jmax = (q0 + 31) >> 6;

  for (int jt = 0; jt <= jmax; jt++){
    int k0 = jt * 64;
    #pragma unroll
    for (int i = 0; i < 2; i++){
      int c = tid + 512 * i;
      int r = c >> 4, cb = c & 15;
      *(s16x8*)(Ks + r * 136 + cb * 8) = *(const s16x8*)(kbase + (size_t)(k0 + r) * D_ + cb * 8);
      int dd = c >> 3, tb = c & 7;
      *(s16x8*)(Vs + dd * 72 + tb * 8) = *(const s16x8*)(vbase + (size_t)dd * T_ + k0 + tb * 8);
    }
    __syncthreads();

    // S = Q K^T (this wave: its 16 q rows x 64 k cols)
    f32x4 sacc[4] = {};
    #pragma unroll
    for (int kk = 0; kk < 4; kk++){
      #pragma unroll
      for (int n = 0; n < 4; n++){
        s16x8 kf = *(const s16x8*)(Ks + (16*n + l15) * 136 + kk * 32 + l4 * 8);
        sacc[n] = __builtin_amdgcn_mfma_f32_16x16x32_bf16(qf[kk], kf, sacc[n], 0, 0, 0);
      }
    }
    if (jt == jmax){
      #pragma unroll
      for (int n = 0; n < 4; n++)
        #pragma unroll
        for (int j = 0; j < 4; j++){
          int qrow = qrow0 + l4*4 + j;
          int kcol = k0 + 16*n + l15;
          if (kcol > qrow) sacc[n][j] = -1e30f;
        }
    }
    // per-row tile max (reduce over l15 within l4 group)
    float mt[4];
    #pragma unroll
    for (int j = 0; j < 4; j++){
      float m = fmaxf(fmaxf(sacc[0][j], sacc[1][j]), fmaxf(sacc[2][j], sacc[3][j]));
      m = fmaxf(m, __shfl_xor(m, 1));
      m = fmaxf(m, __shfl_xor(m, 2));
      m = fmaxf(m, __shfl_xor(m, 4));
      m = fmaxf(m, __shfl_xor(m, 8));
      mt[j] = m;
    }
    // defer-max (T13): only rescale when tile max exceeds running max + 8
    bool need = false;
    #pragma unroll
    for (int j = 0; j < 4; j++) need = need || (mt[j] > mrun[j] + 8.f);
    if (__any((int)need)){
      float alpha[4];
      #pragma unroll
      for (int j = 0; j < 4; j++){
        float mnew = fmaxf(mrun[j], mt[j]);
        alpha[j] = __expf(mrun[j] - mnew);
        mrun[j] = mnew;
        lrun[j] *= alpha[j];
      }
      #pragma unroll
      for (int n8 = 0; n8 < 8; n8++)
        #pragma unroll
        for (int j = 0; j < 4; j++)
          oacc[n8][j] *= alpha[j];
    }
    float rs[4] = {0.f, 0.f, 0.f, 0.f};
    #pragma unroll
    for (int n = 0; n < 4; n++)
      #pragma unroll
      for (int j = 0; j < 4; j++){
        float p = __expf(sacc[n][j] - mrun[j]);
        rs[j] += p;
        Pw[(l4*4 + j) * 72 + 16*n + l15] = f2bf(p);
      }
    #pragma unroll
    for (int j = 0; j < 4; j++){
      float r = rs[j];
      r += __shfl_xor(r, 1); r += __shfl_xor(r, 2);
      r += __shfl_xor(r, 4); r += __shfl_xor(r, 8);
      lrun[j] += r;
    }
    // O += P V (P per-wave private; same-wave ds write->read ordering suffices)
    #pragma unroll
    for (int kk = 0; kk < 2; kk++){
      s16x8 pf = *(const s16x8*)(Pw + l15 * 72 + kk * 32 + l4 * 8);
      #pragma unroll
      for (int n8 = 0; n8 < 8; n8++){
        s16x8 vf = *(const s16x8*)(Vs + (16*n8 + l15) * 72 + kk * 32 + l4 * 8);
        oacc[n8] = __builtin_amdgcn_mfma_f32_16x16x32_bf16(pf, vf, oacc[n8], 0, 0, 0);
      }
    }
    __syncthreads();
  }

  #pragma unroll
  for (int n8 = 0; n8 < 8; n8++)
    #pragma unroll
    for (int j = 0; j < 4; j++){
      int t = qrow0 + l4*4 + j;
      int dcol = 16*n8 + l15;
      float v = oacc[n8][j] / lrun[j];
      O[((size_t)(b * T_ + t)) * C_ + hq * D_ + dcol] = f2bf(v);
    }
}

// ---------------- launch ----------------
extern "C" void kernel_launch(void* const* d_in, const int* in_sizes, int n_in,
                              void* d_out, int out_size, void* d_ws, size_t ws_size,
                              hipStream_t stream){
  const float* x  = (const float*)d_in[0];
  const float* Wq = (const float*)d_in[1];
  const float* Wk = (const float*)d_in[2];
  const float* Wv = (const float*)d_in[3];
  const float* Wo = (const float*)d_in[4];
  float* out = (float*)d_out;

  char* ws = (char*)d_ws;
  size_t off = 0;
  auto alloc = [&](size_t bytes)->void*{
    void* p = ws + off; off += (bytes + 255) & ~(size_t)255; return p;
  };
  ushort* xb  = (ushort*)alloc((size_t)M_ * C_ * 2);
  ushort* Wqt = (ushort*)alloc((size_t)2048 * 2048 * 2);
  ushort* Wkt = (ushort*)alloc((size_t)512 * 2048 * 2);
  ushort* Wvt = (ushort*)alloc((size_t)512 * 2048 * 2);
  ushort* Wot = (ushort*)alloc((size_t)2048 * 2048 * 2);
  ushort* Qb  = (ushort*)alloc((size_t)B_ * H_ * T_ * D_ * 2);
  ushort* Kb  = (ushort*)alloc((size_t)B_ * KV_ * T_ * D_ * 2);
  ushort* Vtb = (ushort*)alloc((size_t)B_ * KV_ * T_ * D_ * 2);
  ushort* Ob  = (ushort*)alloc((size_t)M_ * C_ * 2);

  cvt_f32_bf16<<<2048, 256, 0, stream>>>(x, xb, M_ * C_ / 4);
  transpose_cvt<<<dim3(64, 64), dim3(32, 8), 0, stream>>>(Wq, Wqt, 2048, 2048);
  transpose_cvt<<<dim3(16, 64), dim3(32, 8), 0, stream>>>(Wk, Wkt, 2048, 512);
  transpose_cvt<<<dim3(16, 64), dim3(32, 8), 0, stream>>>(Wv, Wvt, 2048, 512);
  transpose_cvt<<<dim3(64, 64), dim3(32, 8), 0, stream>>>(Wo, Wot, 2048, 2048);

  gemm_bt<1, H_ ><<<dim3(16, 32), 256, 0, stream>>>(xb, Wqt, Qb,  2048, 2048);
  gemm_bt<1, KV_><<<dim3(4, 32),  256, 0, stream>>>(xb, Wkt, Kb,  512,  2048);
  gemm_bt<2, KV_><<<dim3(4, 32),  256, 0, stream>>>(xb, Wvt, Vtb, 512,  2048);

  rope_inplace<<<dim3(T_, B_ * H_),  64, 0, stream>>>(Qb, 0.08838834764831845f);
  rope_inplace<<<dim3(T_, B_ * KV_), 64, 0, stream>>>(Kb, 1.0f);

  attn_kernel2<<<512, 512, 0, stream>>>(Qb, Kb, Vtb, Ob);

  gemm_bt<3, 1><<<dim3(16, 32), 256, 0, stream>>>(Ob, Wot, out, 2048, 2048);
}

// Round 5
// 278.739 us; speedup vs baseline: 1.5521x; 1.2977x over previous
//
#include <hip/hip_runtime.h>
#include <cstdint>
#include <cstddef>

typedef __attribute__((ext_vector_type(4))) float f32x4;
typedef __attribute__((ext_vector_type(8))) short s16x8;
typedef __attribute__((ext_vector_type(4))) short s16x4;

#define B_  2
#define T_  2048
#define C_  2048
#define H_  16
#define KV_ 4
#define D_  128
#define M_  4096   // B*T

static __device__ __forceinline__ float bf2f(ushort u){
  union { float f; uint32_t u; } x; x.u = ((uint32_t)u) << 16; return x.f;
}
static __device__ __forceinline__ ushort f2bf(float f){
  union { float f; uint32_t u; } x; x.f = f;
  uint32_t r = x.u + 0x7FFF + ((x.u >> 16) & 1);
  return (ushort)(r >> 16);
}

// async global->LDS, 16B per lane; dest = wave-uniform base + lane*16
static __device__ __forceinline__ void gl_lds16(const ushort* g, ushort* s){
  __builtin_amdgcn_global_load_lds((const __attribute__((address_space(1))) void*)g,
                                   (__attribute__((address_space(3))) void*)s, 16, 0, 0);
}

// ---------------- fp32 -> bf16 elementwise ----------------
__global__ void cvt_f32_bf16(const float* __restrict__ in, ushort* __restrict__ out, int n4){
  int idx = blockIdx.x * blockDim.x + threadIdx.x;
  int stride = gridDim.x * blockDim.x;
  for (int i = idx; i < n4; i += stride){
    float4 v = ((const float4*)in)[i];
    s16x4 o;
    o[0] = (short)f2bf(v.x); o[1] = (short)f2bf(v.y);
    o[2] = (short)f2bf(v.z); o[3] = (short)f2bf(v.w);
    ((s16x4*)out)[i] = o;
  }
}

// ---------------- fp32 [K][N] -> bf16 [N][K] transpose ----------------
__global__ void transpose_cvt(const float* __restrict__ W, ushort* __restrict__ Wt, int K, int N){
  __shared__ float tile[32][33];
  int n0 = blockIdx.x * 32, k0 = blockIdx.y * 32;
  int tx = threadIdx.x, ty = threadIdx.y;   // 32 x 8
  #pragma unroll
  for (int r = 0; r < 4; r++)
    tile[ty + 8*r][tx] = W[(size_t)(k0 + ty + 8*r) * N + n0 + tx];
  __syncthreads();
  #pragma unroll
  for (int r = 0; r < 4; r++)
    Wt[(size_t)(n0 + ty + 8*r) * K + k0 + tx] = f2bf(tile[tx][ty + 8*r]);
}

// ---------------- fused QKV GEMM: [M,2048] x [3072,2048]^T ----------------
// col <2048 -> Q scatter [B,16,T,D]; <2560 -> K scatter [B,4,T,D]; else -> Vt [B,4,D,T]
__global__ __launch_bounds__(256)
void gemm_qkv(const ushort* __restrict__ A, const ushort* __restrict__ Wt,
              ushort* __restrict__ Qb, ushort* __restrict__ Kb, ushort* __restrict__ Vtb){
  const int Kd = 2048;
  __shared__ __align__(16) ushort As[128 * 32];
  __shared__ __align__(16) ushort Bs[128 * 32];
  int tid = threadIdx.x;
  int w = tid >> 6, l = tid & 63;
  int l15 = l & 15, l4 = l >> 4;
  int rblk = blockIdx.y * 128, cblk = blockIdx.x * 128;
  int rw = (w >> 1) * 64, cw = (w & 1) * 64;

  int ch0 = w * 2, ch1 = w * 2 + 1;
  int srow0 = ch0 * 16 + (l >> 2), srow1 = ch1 * 16 + (l >> 2);
  int scol = (l & 3) * 8;
  const ushort* gA0 = A  + (size_t)(rblk + srow0) * Kd + scol;
  const ushort* gA1 = A  + (size_t)(rblk + srow1) * Kd + scol;
  const ushort* gB0 = Wt + (size_t)(cblk + srow0) * Kd + scol;
  const ushort* gB1 = Wt + (size_t)(cblk + srow1) * Kd + scol;
  ushort* lA0 = As + ch0 * 512;  ushort* lA1 = As + ch1 * 512;
  ushort* lB0 = Bs + ch0 * 512;  ushort* lB1 = Bs + ch1 * 512;

  f32x4 acc[4][4] = {};

  for (int k0 = 0; k0 < Kd; k0 += 32){
    gl_lds16(gA0 + k0, lA0);
    gl_lds16(gA1 + k0, lA1);
    gl_lds16(gB0 + k0, lB0);
    gl_lds16(gB1 + k0, lB1);
    __syncthreads();
    s16x8 af[4], bfv[4];
    #pragma unroll
    for (int m = 0; m < 4; m++)
      af[m] = *(const s16x8*)(As + (rw + 16*m + l15) * 32 + l4 * 8);
    #pragma unroll
    for (int n = 0; n < 4; n++)
      bfv[n] = *(const s16x8*)(Bs + (cw + 16*n + l15) * 32 + l4 * 8);
    #pragma unroll
    for (int m = 0; m < 4; m++)
      #pragma unroll
      for (int n = 0; n < 4; n++)
        acc[m][n] = __builtin_amdgcn_mfma_f32_16x16x32_bf16(af[m], bfv[n], acc[m][n], 0, 0, 0);
    __syncthreads();
  }

  #pragma unroll
  for (int m = 0; m < 4; m++){
    #pragma unroll
    for (int n = 0; n < 4; n++){
      #pragma unroll
      for (int j = 0; j < 4; j++){
        int row = rblk + rw + 16*m + l4*4 + j;
        int col = cblk + cw + 16*n + l15;
        int t = row & (T_ - 1), b = row >> 11;
        ushort v = f2bf(acc[m][n][j]);
        if (cblk < 2048){
          int hh = col >> 7, d = col & 127;
          Qb[(((size_t)(b * H_ + hh)) * T_ + t) * D_ + d] = v;
        } else if (cblk < 2560){
          int c2 = col - 2048;
          int hh = c2 >> 7, d = c2 & 127;
          Kb[(((size_t)(b * KV_ + hh)) * T_ + t) * D_ + d] = v;
        } else {
          int c2 = col - 2560;
          int hh = c2 >> 7, d = c2 & 127;
          Vtb[(((size_t)(b * KV_ + hh)) * D_ + d) * T_ + t] = v;
        }
      }
    }
  }
}

// ---------------- O-proj GEMM: fp32 out [M,N] ----------------
__global__ __launch_bounds__(256)
void gemm_out(const ushort* __restrict__ A, const ushort* __restrict__ Bt,
              float* __restrict__ Cout, int N, int Kd){
  __shared__ __align__(16) ushort As[128 * 32];
  __shared__ __align__(16) ushort Bs[128 * 32];
  int tid = threadIdx.x;
  int w = tid >> 6, l = tid & 63;
  int l15 = l & 15, l4 = l >> 4;
  int rblk = blockIdx.y * 128, cblk = blockIdx.x * 128;
  int rw = (w >> 1) * 64, cw = (w & 1) * 64;

  int ch0 = w * 2, ch1 = w * 2 + 1;
  int srow0 = ch0 * 16 + (l >> 2), srow1 = ch1 * 16 + (l >> 2);
  int scol = (l & 3) * 8;
  const ushort* gA0 = A  + (size_t)(rblk + srow0) * Kd + scol;
  const ushort* gA1 = A  + (size_t)(rblk + srow1) * Kd + scol;
  const ushort* gB0 = Bt + (size_t)(cblk + srow0) * Kd + scol;
  const ushort* gB1 = Bt + (size_t)(cblk + srow1) * Kd + scol;
  ushort* lA0 = As + ch0 * 512;  ushort* lA1 = As + ch1 * 512;
  ushort* lB0 = Bs + ch0 * 512;  ushort* lB1 = Bs + ch1 * 512;

  f32x4 acc[4][4] = {};

  for (int k0 = 0; k0 < Kd; k0 += 32){
    gl_lds16(gA0 + k0, lA0);
    gl_lds16(gA1 + k0, lA1);
    gl_lds16(gB0 + k0, lB0);
    gl_lds16(gB1 + k0, lB1);
    __syncthreads();
    s16x8 af[4], bfv[4];
    #pragma unroll
    for (int m = 0; m < 4; m++)
      af[m] = *(const s16x8*)(As + (rw + 16*m + l15) * 32 + l4 * 8);
    #pragma unroll
    for (int n = 0; n < 4; n++)
      bfv[n] = *(const s16x8*)(Bs + (cw + 16*n + l15) * 32 + l4 * 8);
    #pragma unroll
    for (int m = 0; m < 4; m++)
      #pragma unroll
      for (int n = 0; n < 4; n++)
        acc[m][n] = __builtin_amdgcn_mfma_f32_16x16x32_bf16(af[m], bfv[n], acc[m][n], 0, 0, 0);
    __syncthreads();
  }

  #pragma unroll
  for (int m = 0; m < 4; m++)
    #pragma unroll
    for (int n = 0; n < 4; n++)
      #pragma unroll
      for (int j = 0; j < 4; j++){
        int row = rblk + rw + 16*m + l4*4 + j;
        int col = cblk + cw + 16*n + l15;
        Cout[(size_t)row * N + col] = acc[m][n][j];
      }
}

// ---------------- RoPE in place on [B*NH, T, D], vectorized ----------------
__global__ __launch_bounds__(256)
void rope_inplace2(ushort* __restrict__ X, float scale){
  int tr = threadIdx.x >> 4;          // 0..15 row in block
  int j  = threadIdx.x & 15;          // 16 threads per row, 4 pairs each
  int t  = blockIdx.x * 16 + tr;
  int bh = blockIdx.y;
  ushort* row = X + ((size_t)bh * T_ + t) * D_;
  s16x4 lo = *(const s16x4*)(row + j*4);
  s16x4 hi = *(const s16x4*)(row + 64 + j*4);
  s16x4 olo, ohi;
  #pragma unroll
  for (int i = 0; i < 4; i++){
    int d = j*4 + i;
    float invf = exp2f(-(float)d * 0.2076205059304602f);  // log2(10000)/64
    float s, c;
    __sincosf((float)t * invf, &s, &c);
    float q1 = bf2f((ushort)lo[i]);
    float q2 = bf2f((ushort)hi[i]);
    olo[i] = (short)f2bf((q1 * c - q2 * s) * scale);
    ohi[i] = (short)f2bf((q2 * c + q1 * s) * scale);
  }
  *(s16x4*)(row + j*4) = olo;
  *(s16x4*)(row + 64 + j*4) = ohi;
}

// ---------------- causal GQA flash attention (v3) ----------------
// Block = (b, kvh, 32-row q tile), 8 waves = 4 heads x 2 sub-tiles.
// Reg-staged K/V with load-early overlap; XOR-swizzled Ks/Vs; balanced qt pairing.
__global__ __launch_bounds__(512, 4)
void attn_kernel3(const ushort* __restrict__ Q, const ushort* __restrict__ Kc,
                  const ushort* __restrict__ Vt, ushort* __restrict__ O){
  __shared__ __align__(16) ushort Ks[64 * 128];      // swizzled: byte ^= (row&7)<<4
  __shared__ __align__(16) ushort Vs[128 * 64];      // swizzled
  __shared__ __align__(16) ushort Ps[8 * 16 * 72];   // per-wave, padded
  int bid = blockIdx.x;
  int i  = bid >> 3;
  int qt = (i < 32) ? (63 - i) : (i - 32);   // pair sums constant per CU
  int sub = bid & 7;
  int b = sub >> 2, kvh = sub & 3;
  int tid = threadIdx.x, w = tid >> 6, l = tid & 63;
  int l15 = l & 15, l4 = l >> 4;
  int sw3 = (l15 & 7) << 3;                  // read-side swizzle (ushort units)
  int q0 = qt * 32;
  int hq = kvh * 4 + (w >> 1);
  int qrow0 = q0 + (w & 1) * 16;

  s16x8 qf[4];
  const ushort* qbase = Q + (((size_t)(b * H_ + hq)) * T_ + qrow0 + l15) * D_;
  #pragma unroll
  for (int kk = 0; kk < 4; kk++)
    qf[kk] = *(const s16x8*)(qbase + kk * 32 + l4 * 8);

  f32x4 oacc[8] = {};
  float mrun[4] = {-1e30f, -1e30f, -1e30f, -1e30f};
  float lrun[4] = {0.f, 0.f, 0.f, 0.f};
  ushort* Pw = Ps + w * 16 * 72;

  const ushort* kbase = Kc + ((size_t)(b * KV_ + kvh)) * T_ * D_;
  const ushort* vbase = Vt + ((size_t)(b * KV_ + kvh)) * D_ * T_;
  int jmax = (q0 + 31) >> 6;

  // staging geometry (512 threads, 2 chunks each for K and V)
  int kr0 = tid >> 4, kcb = tid & 15;              // K rows 0..31 (+32), 16B chunk
  int vd0 = tid >> 3, vtb = tid & 7;               // V rows 0..63 (+64), 16B chunk
  int ksoff = kr0 * 128 + ((kcb * 8) ^ ((kr0 & 7) << 3));
  int vsoff = vd0 * 64  + ((vtb * 8) ^ ((vd0 & 7) << 3));
  const ushort* kg = kbase + (size_t)kr0 * D_ + kcb * 8;
  const ushort* vg = vbase + (size_t)vd0 * T_ + vtb * 8;

  s16x8 kreg0, kreg1, vreg0, vreg1;
  // prologue: tile 0
  kreg0 = *(const s16x8*)(kg);
  kreg1 = *(const s16x8*)(kg + (size_t)32 * D_);
  vreg0 = *(const s16x8*)(vg);
  vreg1 = *(const s16x8*)(vg + (size_t)64 * T_);

  for (int jt = 0; jt <= jmax; jt++){
    __syncthreads();                       // all waves done reading prev tile
    *(s16x8*)(Ks + ksoff)            = kreg0;
    *(s16x8*)(Ks + ksoff + 32 * 128) = kreg1;
    *(s16x8*)(Vs + vsoff)            = vreg0;
    *(s16x8*)(Vs + vsoff + 64 * 64)  = vreg1;
    __syncthreads();                       // writes visible; no vmem in flight here
    if (jt < jmax){
      int k1 = (jt + 1) * 64;
      kreg0 = *(const s16x8*)(kg + (size_t)k1 * D_);
      kreg1 = *(const s16x8*)(kg + (size_t)(k1 + 32) * D_);
      vreg0 = *(const s16x8*)(vg + k1);
      vreg1 = *(const s16x8*)(vg + (size_t)64 * T_ + k1);
    }
    int k0 = jt * 64;

    // S = Q K^T
    f32x4 sacc[4] = {};
    __builtin_amdgcn_s_setprio(1);
    #pragma unroll
    for (int kk = 0; kk < 4; kk++){
      #pragma unroll
      for (int n = 0; n < 4; n++){
        s16x8 kf = *(const s16x8*)(Ks + (16*n + l15) * 128 + (((kk*32 + l4*8)) ^ sw3));
        sacc[n] = __builtin_amdgcn_mfma_f32_16x16x32_bf16(qf[kk], kf, sacc[n], 0, 0, 0);
      }
    }
    __builtin_amdgcn_s_setprio(0);
    if (jt == jmax){
      #pragma unroll
      for (int n = 0; n < 4; n++)
        #pragma unroll
        for (int j = 0; j < 4; j++){
          int qrow = qrow0 + l4*4 + j;
          int kcol = k0 + 16*n + l15;
          if (kcol > qrow) sacc[n][j] = -1e30f;
        }
    }
    float mt[4];
    #pragma unroll
    for (int j = 0; j < 4; j++){
      float m = fmaxf(fmaxf(sacc[0][j], sacc[1][j]), fmaxf(sacc[2][j], sacc[3][j]));
      m = fmaxf(m, __shfl_xor(m, 1));
      m = fmaxf(m, __shfl_xor(m, 2));
      m = fmaxf(m, __shfl_xor(m, 4));
      m = fmaxf(m, __shfl_xor(m, 8));
      mt[j] = m;
    }
    bool need = false;
    #pragma unroll
    for (int j = 0; j < 4; j++) need = need || (mt[j] > mrun[j] + 8.f);
    if (__any((int)need)){
      float alpha[4];
      #pragma unroll
      for (int j = 0; j < 4; j++){
        float mnew = fmaxf(mrun[j], mt[j]);
        alpha[j] = __expf(mrun[j] - mnew);
        mrun[j] = mnew;
        lrun[j] *= alpha[j];
      }
      #pragma unroll
      for (int n8 = 0; n8 < 8; n8++)
        #pragma unroll
        for (int j = 0; j < 4; j++)
          oacc[n8][j] *= alpha[j];
    }
    float rs[4] = {0.f, 0.f, 0.f, 0.f};
    #pragma unroll
    for (int n = 0; n < 4; n++)
      #pragma unroll
      for (int j = 0; j < 4; j++){
        float p = __expf(sacc[n][j] - mrun[j]);
        rs[j] += p;
        Pw[(l4*4 + j) * 72 + 16*n + l15] = f2bf(p);
      }
    #pragma unroll
    for (int j = 0; j < 4; j++){
      float r = rs[j];
      r += __shfl_xor(r, 1); r += __shfl_xor(r, 2);
      r += __shfl_xor(r, 4); r += __shfl_xor(r, 8);
      lrun[j] += r;
    }
    // O += P V
    __builtin_amdgcn_s_setprio(1);
    #pragma unroll
    for (int kk = 0; kk < 2; kk++){
      s16x8 pf = *(const s16x8*)(Pw + l15 * 72 + kk * 32 + l4 * 8);
      #pragma unroll
      for (int n8 = 0; n8 < 8; n8++){
        s16x8 vf = *(const s16x8*)(Vs + (16*n8 + l15) * 64 + ((kk*32 + l4*8) ^ sw3));
        oacc[n8] = __builtin_amdgcn_mfma_f32_16x16x32_bf16(pf, vf, oacc[n8], 0, 0, 0);
      }
    }
    __builtin_amdgcn_s_setprio(0);
  }

  #pragma unroll
  for (int n8 = 0; n8 < 8; n8++)
    #pragma unroll
    for (int j = 0; j < 4; j++){
      int t = qrow0 + l4*4 + j;
      int dcol = 16*n8 + l15;
      float v = oacc[n8][j] / lrun[j];
      O[((size_t)(b * T_ + t)) * C_ + hq * D_ + dcol] = f2bf(v);
    }
}

// ---------------- launch ----------------
extern "C" void kernel_launch(void* const* d_in, const int* in_sizes, int n_in,
                              void* d_out, int out_size, void* d_ws, size_t ws_size,
                              hipStream_t stream){
  const float* x  = (const float*)d_in[0];
  const float* Wq = (const float*)d_in[1];
  const float* Wk = (const float*)d_in[2];
  const float* Wv = (const float*)d_in[3];
  const float* Wo = (const float*)d_in[4];
  float* out = (float*)d_out;

  char* ws = (char*)d_ws;
  size_t off = 0;
  auto alloc = [&](size_t bytes)->void*{
    void* p = ws + off; off += (bytes + 255) & ~(size_t)255; return p;
  };
  ushort* xb   = (ushort*)alloc((size_t)M_ * C_ * 2);
  ushort* Wcat = (ushort*)alloc((size_t)3072 * 2048 * 2);   // [Wq|Wk|Wv]^T rows
  ushort* Wot  = (ushort*)alloc((size_t)2048 * 2048 * 2);
  ushort* Qb   = (ushort*)alloc((size_t)B_ * H_ * T_ * D_ * 2);
  ushort* Kb   = (ushort*)alloc((size_t)B_ * KV_ * T_ * D_ * 2);
  ushort* Vtb  = (ushort*)alloc((size_t)B_ * KV_ * T_ * D_ * 2);
  ushort* Ob   = (ushort*)alloc((size_t)M_ * C_ * 2);

  cvt_f32_bf16<<<2048, 256, 0, stream>>>(x, xb, M_ * C_ / 4);
  transpose_cvt<<<dim3(64, 64), dim3(32, 8), 0, stream>>>(Wq, Wcat, 2048, 2048);
  transpose_cvt<<<dim3(16, 64), dim3(32, 8), 0, stream>>>(Wk, Wcat + (size_t)2048*2048, 2048, 512);
  transpose_cvt<<<dim3(16, 64), dim3(32, 8), 0, stream>>>(Wv, Wcat + (size_t)2560*2048, 2048, 512);
  transpose_cvt<<<dim3(64, 64), dim3(32, 8), 0, stream>>>(Wo, Wot, 2048, 2048);

  gemm_qkv<<<dim3(24, 32), 256, 0, stream>>>(xb, Wcat, Qb, Kb, Vtb);

  rope_inplace2<<<dim3(T_/16, B_ * H_),  256, 0, stream>>>(Qb, 0.08838834764831845f);
  rope_inplace2<<<dim3(T_/16, B_ * KV_), 256, 0, stream>>>(Kb, 1.0f);

  attn_kernel3<<<512, 512, 0, stream>>>(Qb, Kb, Vtb, Ob);

  gemm_out<<<dim3(16, 32), 256, 0, stream>>>(Ob, Wot, out, 2048, 2048);
}

// Round 6
// 242.878 us; speedup vs baseline: 1.7813x; 1.1476x over previous
//
#include <hip/hip_runtime.h>
#include <cstdint>
#include <cstddef>

typedef __attribute__((ext_vector_type(4))) float f32x4;
typedef __attribute__((ext_vector_type(8))) short s16x8;
typedef __attribute__((ext_vector_type(4))) short s16x4;

#define B_  2
#define T_  2048
#define C_  2048
#define H_  16
#define KV_ 4
#define D_  128
#define M_  4096   // B*T

static __device__ __forceinline__ float bf2f(ushort u){
  union { float f; uint32_t u; } x; x.u = ((uint32_t)u) << 16; return x.f;
}
static __device__ __forceinline__ ushort f2bf(float f){
  union { float f; uint32_t u; } x; x.f = f;
  uint32_t r = x.u + 0x7FFF + ((x.u >> 16) & 1);
  return (ushort)(r >> 16);
}

// async global->LDS, 16B per lane; dest = wave-uniform base + lane*16
static __device__ __forceinline__ void gl_lds16(const ushort* g, ushort* s){
  __builtin_amdgcn_global_load_lds((const __attribute__((address_space(1))) void*)g,
                                   (__attribute__((address_space(3))) void*)s, 16, 0, 0);
}

// ---------------- fp32 -> bf16 elementwise ----------------
__global__ void cvt_f32_bf16(const float* __restrict__ in, ushort* __restrict__ out, int n4){
  int idx = blockIdx.x * blockDim.x + threadIdx.x;
  int stride = gridDim.x * blockDim.x;
  for (int i = idx; i < n4; i += stride){
    float4 v = ((const float4*)in)[i];
    s16x4 o;
    o[0] = (short)f2bf(v.x); o[1] = (short)f2bf(v.y);
    o[2] = (short)f2bf(v.z); o[3] = (short)f2bf(v.w);
    ((s16x4*)out)[i] = o;
  }
}

// ---------------- fp32 [K][N] -> bf16 [N][K] transpose ----------------
__global__ void transpose_cvt(const float* __restrict__ W, ushort* __restrict__ Wt, int K, int N){
  __shared__ float tile[32][33];
  int n0 = blockIdx.x * 32, k0 = blockIdx.y * 32;
  int tx = threadIdx.x, ty = threadIdx.y;   // 32 x 8
  #pragma unroll
  for (int r = 0; r < 4; r++)
    tile[ty + 8*r][tx] = W[(size_t)(k0 + ty + 8*r) * N + n0 + tx];
  __syncthreads();
  #pragma unroll
  for (int r = 0; r < 4; r++)
    Wt[(size_t)(n0 + ty + 8*r) * K + k0 + tx] = f2bf(tile[tx][ty + 8*r]);
}

// ---------------- deep-pipelined GEMM: C = A[M,K] x Bt[N,K]^T ----------------
// BM=BN=128, BK=64, 512 threads (8 waves 2Mx4N), 4 K-tile LDS buffers, depth-3
// prefetch with counted vmcnt. T2 swizzle on LDS; T5 setprio around MFMA.
// MODE 0: fp32 out row-major [M,N]. MODE 1: QKV scatter (N=3072).
template<int MODE>
__global__ __launch_bounds__(512)
void gemm_deep(const ushort* __restrict__ A, const ushort* __restrict__ Bt,
               void* __restrict__ C0, void* __restrict__ C1, void* __restrict__ C2,
               int N, int Kd, int nbx){
  __shared__ __align__(16) ushort Abuf[4][8192];   // [buf][128 rows x 64 k]
  __shared__ __align__(16) ushort Bbuf[4][8192];
  int tid = threadIdx.x, w = tid >> 6, l = tid & 63;
  int l15 = l & 15, l4 = l >> 4;

  // bijective chunked XCD swizzle (gridDim.x % 8 == 0)
  int cpx = gridDim.x >> 3;
  int logical = (blockIdx.x & 7) * cpx + (blockIdx.x >> 3);
  int bx = logical % nbx, by = logical / nbx;
  int rblk = by * 128, cblk = bx * 128;
  int wm = w & 1, wn = w >> 1;

  // staging geometry: volley = 512thr x 16B = 8KB = 64 rows; 2 volleys per operand
  int sr = tid >> 3;                               // row 0..63
  int sc = ((tid & 7) * 8) ^ ((sr & 7) << 3);      // pre-swizzled source col (ushort)
  const ushort* gA = A  + (size_t)(rblk + sr) * Kd + sc;
  const ushort* gB = Bt + (size_t)(cblk + sr) * Kd + sc;
  size_t rowK = (size_t)64 * Kd;
  int wb = w * 512;                                // wave LDS base (ushort) within volley

  auto stage = [&](int t){
    int bsel = t & 3; int koff = t * 64;
    gl_lds16(gA + koff,        &Abuf[bsel][wb]);
    gl_lds16(gA + rowK + koff, &Abuf[bsel][4096 + wb]);
    gl_lds16(gB + koff,        &Bbuf[bsel][wb]);
    gl_lds16(gB + rowK + koff, &Bbuf[bsel][4096 + wb]);
  };

  // fragment read offsets (swizzled): row&7 == l15&7
  int arow = wm * 64 + l15;
  int brow = wn * 32 + l15;
  int kx0 = (l4 * 8) ^ ((l15 & 7) << 3);
  int kx1 = (32 + l4 * 8) ^ ((l15 & 7) << 3);

  f32x4 acc[4][2] = {};

  auto phase = [&](int t, int dostage, int vm){
    const ushort* Ab = Abuf[t & 3];
    const ushort* Bb = Bbuf[t & 3];
    s16x8 a[4][2], b[2][2];
    #pragma unroll
    for (int m = 0; m < 4; m++){
      a[m][0] = *(const s16x8*)(Ab + (arow + m*16) * 64 + kx0);
      a[m][1] = *(const s16x8*)(Ab + (arow + m*16) * 64 + kx1);
    }
    #pragma unroll
    for (int n = 0; n < 2; n++){
      b[n][0] = *(const s16x8*)(Bb + (brow + n*16) * 64 + kx0);
      b[n][1] = *(const s16x8*)(Bb + (brow + n*16) * 64 + kx1);
    }
    if (dostage) stage(t + 3);
    if (vm == 8)      { asm volatile("s_waitcnt vmcnt(8)" ::: "memory"); }
    else if (vm == 4) { asm volatile("s_waitcnt vmcnt(4)" ::: "memory"); }
    else if (vm == 0) { asm volatile("s_waitcnt vmcnt(0)" ::: "memory"); }
    if (vm >= 0) __builtin_amdgcn_sched_barrier(0);
    __builtin_amdgcn_s_barrier();
    asm volatile("s_waitcnt lgkmcnt(0)" ::: "memory");
    __builtin_amdgcn_sched_barrier(0);
    __builtin_amdgcn_s_setprio(1);
    #pragma unroll
    for (int m = 0; m < 4; m++)
      #pragma unroll
      for (int n = 0; n < 2; n++){
        acc[m][n] = __builtin_amdgcn_mfma_f32_16x16x32_bf16(a[m][0], b[n][0], acc[m][n], 0, 0, 0);
        acc[m][n] = __builtin_amdgcn_mfma_f32_16x16x32_bf16(a[m][1], b[n][1], acc[m][n], 0, 0, 0);
      }
    __builtin_amdgcn_s_setprio(0);
    __builtin_amdgcn_s_barrier();
  };

  // prologue: stage tiles 0..2, wait tile 0 (8 = tiles 1,2 still in flight)
  stage(0); stage(1); stage(2);
  asm volatile("s_waitcnt vmcnt(8)" ::: "memory");
  __builtin_amdgcn_s_barrier();

  int nt = Kd >> 6;                                // 32
  for (int t = 0; t < nt - 3; ++t) phase(t, 1, 8); // steady: stage t+3, wait t+1
  phase(nt - 3, 0, 4);
  phase(nt - 2, 0, 0);
  phase(nt - 1, 0, -1);

  // epilogue
  #pragma unroll
  for (int m = 0; m < 4; m++){
    #pragma unroll
    for (int n = 0; n < 2; n++){
      #pragma unroll
      for (int j = 0; j < 4; j++){
        int row = rblk + wm*64 + m*16 + l4*4 + j;
        int col = cblk + wn*32 + n*16 + l15;
        float v = acc[m][n][j];
        if (MODE == 0){
          ((float*)C0)[(size_t)row * N + col] = v;
        } else {
          int t = row & (T_ - 1), bb = row >> 11;
          ushort bv = f2bf(v);
          if (cblk < 2048){
            int hh = col >> 7, d = col & 127;
            ((ushort*)C0)[(((size_t)(bb * H_ + hh)) * T_ + t) * D_ + d] = bv;
          } else if (cblk < 2560){
            int c2 = col - 2048;
            int hh = c2 >> 7, d = c2 & 127;
            ((ushort*)C1)[(((size_t)(bb * KV_ + hh)) * T_ + t) * D_ + d] = bv;
          } else {
            int c2 = col - 2560;
            int hh = c2 >> 7, d = c2 & 127;
            ((ushort*)C2)[(((size_t)(bb * KV_ + hh)) * D_ + d) * T_ + t] = bv;
          }
        }
      }
    }
  }
}

// ---------------- RoPE in place on [B*NH, T, D], vectorized ----------------
__global__ __launch_bounds__(256)
void rope_inplace2(ushort* __restrict__ X, float scale){
  int tr = threadIdx.x >> 4;          // 0..15 row in block
  int j  = threadIdx.x & 15;          // 16 threads per row, 4 pairs each
  int t  = blockIdx.x * 16 + tr;
  int bh = blockIdx.y;
  ushort* row = X + ((size_t)bh * T_ + t) * D_;
  s16x4 lo = *(const s16x4*)(row + j*4);
  s16x4 hi = *(const s16x4*)(row + 64 + j*4);
  s16x4 olo, ohi;
  #pragma unroll
  for (int i = 0; i < 4; i++){
    int d = j*4 + i;
    float invf = exp2f(-(float)d * 0.2076205059304602f);  // log2(10000)/64
    float s, c;
    __sincosf((float)t * invf, &s, &c);
    float q1 = bf2f((ushort)lo[i]);
    float q2 = bf2f((ushort)hi[i]);
    olo[i] = (short)f2bf((q1 * c - q2 * s) * scale);
    ohi[i] = (short)f2bf((q2 * c + q1 * s) * scale);
  }
  *(s16x4*)(row + j*4) = olo;
  *(s16x4*)(row + 64 + j*4) = ohi;
}

// ---------------- causal GQA flash attention (v3) ----------------
// Block = (b, kvh, 32-row q tile), 8 waves = 4 heads x 2 sub-tiles.
// Reg-staged K/V with load-early overlap; XOR-swizzled Ks/Vs; balanced qt pairing.
__global__ __launch_bounds__(512, 4)
void attn_kernel3(const ushort* __restrict__ Q, const ushort* __restrict__ Kc,
                  const ushort* __restrict__ Vt, ushort* __restrict__ O){
  __shared__ __align__(16) ushort Ks[64 * 128];      // swizzled: byte ^= (row&7)<<4
  __shared__ __align__(16) ushort Vs[128 * 64];      // swizzled
  __shared__ __align__(16) ushort Ps[8 * 16 * 72];   // per-wave, padded
  int bid = blockIdx.x;
  int i  = bid >> 3;
  int qt = (i < 32) ? (63 - i) : (i - 32);   // pair sums constant per CU
  int sub = bid & 7;
  int b = sub >> 2, kvh = sub & 3;
  int tid = threadIdx.x, w = tid >> 6, l = tid & 63;
  int l15 = l & 15, l4 = l >> 4;
  int sw3 = (l15 & 7) << 3;                  // read-side swizzle (ushort units)
  int q0 = qt * 32;
  int hq = kvh * 4 + (w >> 1);
  int qrow0 = q0 + (w & 1) * 16;

  s16x8 qf[4];
  const ushort* qbase = Q + (((size_t)(b * H_ + hq)) * T_ + qrow0 + l15) * D_;
  #pragma unroll
  for (int kk = 0; kk < 4; kk++)
    qf[kk] = *(const s16x8*)(qbase + kk * 32 + l4 * 8);

  f32x4 oacc[8] = {};
  float mrun[4] = {-1e30f, -1e30f, -1e30f, -1e30f};
  float lrun[4] = {0.f, 0.f, 0.f, 0.f};
  ushort* Pw = Ps + w * 16 * 72;

  const ushort* kbase = Kc + ((size_t)(b * KV_ + kvh)) * T_ * D_;
  const ushort* vbase = Vt + ((size_t)(b * KV_ + kvh)) * D_ * T_;
  int jmax = (q0 + 31) >> 6;

  // staging geometry (512 threads, 2 chunks each for K and V)
  int kr0 = tid >> 4, kcb = tid & 15;              // K rows 0..31 (+32), 16B chunk
  int vd0 = tid >> 3, vtb = tid & 7;               // V rows 0..63 (+64), 16B chunk
  int ksoff = kr0 * 128 + ((kcb * 8) ^ ((kr0 & 7) << 3));
  int vsoff = vd0 * 64  + ((vtb * 8) ^ ((vd0 & 7) << 3));
  const ushort* kg = kbase + (size_t)kr0 * D_ + kcb * 8;
  const ushort* vg = vbase + (size_t)vd0 * T_ + vtb * 8;

  s16x8 kreg0, kreg1, vreg0, vreg1;
  // prologue: tile 0
  kreg0 = *(const s16x8*)(kg);
  kreg1 = *(const s16x8*)(kg + (size_t)32 * D_);
  vreg0 = *(const s16x8*)(vg);
  vreg1 = *(const s16x8*)(vg + (size_t)64 * T_);

  for (int jt = 0; jt <= jmax; jt++){
    __syncthreads();                       // all waves done reading prev tile
    *(s16x8*)(Ks + ksoff)            = kreg0;
    *(s16x8*)(Ks + ksoff + 32 * 128) = kreg1;
    *(s16x8*)(Vs + vsoff)            = vreg0;
    *(s16x8*)(Vs + vsoff + 64 * 64)  = vreg1;
    __syncthreads();                       // writes visible; no vmem in flight here
    if (jt < jmax){
      int k1 = (jt + 1) * 64;
      kreg0 = *(const s16x8*)(kg + (size_t)k1 * D_);
      kreg1 = *(const s16x8*)(kg + (size_t)(k1 + 32) * D_);
      vreg0 = *(const s16x8*)(vg + k1);
      vreg1 = *(const s16x8*)(vg + (size_t)64 * T_ + k1);
    }
    int k0 = jt * 64;

    // S = Q K^T
    f32x4 sacc[4] = {};
    __builtin_amdgcn_s_setprio(1);
    #pragma unroll
    for (int kk = 0; kk < 4; kk++){
      #pragma unroll
      for (int n = 0; n < 4; n++){
        s16x8 kf = *(const s16x8*)(Ks + (16*n + l15) * 128 + (((kk*32 + l4*8)) ^ sw3));
        sacc[n] = __builtin_amdgcn_mfma_f32_16x16x32_bf16(qf[kk], kf, sacc[n], 0, 0, 0);
      }
    }
    __builtin_amdgcn_s_setprio(0);
    if (jt == jmax){
      #pragma unroll
      for (int n = 0; n < 4; n++)
        #pragma unroll
        for (int j = 0; j < 4; j++){
          int qrow = qrow0 + l4*4 + j;
          int kcol = k0 + 16*n + l15;
          if (kcol > qrow) sacc[n][j] = -1e30f;
        }
    }
    float mt[4];
    #pragma unroll
    for (int j = 0; j < 4; j++){
      float m = fmaxf(fmaxf(sacc[0][j], sacc[1][j]), fmaxf(sacc[2][j], sacc[3][j]));
      m = fmaxf(m, __shfl_xor(m, 1));
      m = fmaxf(m, __shfl_xor(m, 2));
      m = fmaxf(m, __shfl_xor(m, 4));
      m = fmaxf(m, __shfl_xor(m, 8));
      mt[j] = m;
    }
    bool need = false;
    #pragma unroll
    for (int j = 0; j < 4; j++) need = need || (mt[j] > mrun[j] + 8.f);
    if (__any((int)need)){
      float alpha[4];
      #pragma unroll
      for (int j = 0; j < 4; j++){
        float mnew = fmaxf(mrun[j], mt[j]);
        alpha[j] = __expf(mrun[j] - mnew);
        mrun[j] = mnew;
        lrun[j] *= alpha[j];
      }
      #pragma unroll
      for (int n8 = 0; n8 < 8; n8++)
        #pragma unroll
        for (int j = 0; j < 4; j++)
          oacc[n8][j] *= alpha[j];
    }
    float rs[4] = {0.f, 0.f, 0.f, 0.f};
    #pragma unroll
    for (int n = 0; n < 4; n++)
      #pragma unroll
      for (int j = 0; j < 4; j++){
        float p = __expf(sacc[n][j] - mrun[j]);
        rs[j] += p;
        Pw[(l4*4 + j) * 72 + 16*n + l15] = f2bf(p);
      }
    #pragma unroll
    for (int j = 0; j < 4; j++){
      float r = rs[j];
      r += __shfl_xor(r, 1); r += __shfl_xor(r, 2);
      r += __shfl_xor(r, 4); r += __shfl_xor(r, 8);
      lrun[j] += r;
    }
    // O += P V
    __builtin_amdgcn_s_setprio(1);
    #pragma unroll
    for (int kk = 0; kk < 2; kk++){
      s16x8 pf = *(const s16x8*)(Pw + l15 * 72 + kk * 32 + l4 * 8);
      #pragma unroll
      for (int n8 = 0; n8 < 8; n8++){
        s16x8 vf = *(const s16x8*)(Vs + (16*n8 + l15) * 64 + ((kk*32 + l4*8) ^ sw3));
        oacc[n8] = __builtin_amdgcn_mfma_f32_16x16x32_bf16(pf, vf, oacc[n8], 0, 0, 0);
      }
    }
    __builtin_amdgcn_s_setprio(0);
  }

  #pragma unroll
  for (int n8 = 0; n8 < 8; n8++)
    #pragma unroll
    for (int j = 0; j < 4; j++){
      int t = qrow0 + l4*4 + j;
      int dcol = 16*n8 + l15;
      float v = oacc[n8][j] / lrun[j];
      O[((size_t)(b * T_ + t)) * C_ + hq * D_ + dcol] = f2bf(v);
    }
}

// ---------------- launch ----------------
extern "C" void kernel_launch(void* const* d_in, const int* in_sizes, int n_in,
                              void* d_out, int out_size, void* d_ws, size_t ws_size,
                              hipStream_t stream){
  const float* x  = (const float*)d_in[0];
  const float* Wq = (const float*)d_in[1];
  const float* Wk = (const float*)d_in[2];
  const float* Wv = (const float*)d_in[3];
  const float* Wo = (const float*)d_in[4];
  float* out = (float*)d_out;

  char* ws = (char*)d_ws;
  size_t off = 0;
  auto alloc = [&](size_t bytes)->void*{
    void* p = ws + off; off += (bytes + 255) & ~(size_t)255; return p;
  };
  ushort* xb   = (ushort*)alloc((size_t)M_ * C_ * 2);
  ushort* Wcat = (ushort*)alloc((size_t)3072 * 2048 * 2);   // [Wq|Wk|Wv]^T rows
  ushort* Wot  = (ushort*)alloc((size_t)2048 * 2048 * 2);
  ushort* Qb   = (ushort*)alloc((size_t)B_ * H_ * T_ * D_ * 2);
  ushort* Kb   = (ushort*)alloc((size_t)B_ * KV_ * T_ * D_ * 2);
  ushort* Vtb  = (ushort*)alloc((size_t)B_ * KV_ * T_ * D_ * 2);
  ushort* Ob   = (ushort*)alloc((size_t)M_ * C_ * 2);

  cvt_f32_bf16<<<2048, 256, 0, stream>>>(x, xb, M_ * C_ / 4);
  transpose_cvt<<<dim3(64, 64), dim3(32, 8), 0, stream>>>(Wq, Wcat, 2048, 2048);
  transpose_cvt<<<dim3(16, 64), dim3(32, 8), 0, stream>>>(Wk, Wcat + (size_t)2048*2048, 2048, 512);
  transpose_cvt<<<dim3(16, 64), dim3(32, 8), 0, stream>>>(Wv, Wcat + (size_t)2560*2048, 2048, 512);
  transpose_cvt<<<dim3(64, 64), dim3(32, 8), 0, stream>>>(Wo, Wot, 2048, 2048);

  // fused QKV projection: [4096,2048] x [3072,2048]^T, scatter epilogue
  gemm_deep<1><<<768, 512, 0, stream>>>(xb, Wcat, Qb, Kb, Vtb, 3072, 2048, 24);

  rope_inplace2<<<dim3(T_/16, B_ * H_),  256, 0, stream>>>(Qb, 0.08838834764831845f);
  rope_inplace2<<<dim3(T_/16, B_ * KV_), 256, 0, stream>>>(Kb, 1.0f);

  attn_kernel3<<<512, 512, 0, stream>>>(Qb, Kb, Vtb, Ob);

  // output projection: [4096,2048] x [2048,2048]^T -> fp32
  gemm_deep<0><<<512, 512, 0, stream>>>(Ob, Wot, out, nullptr, nullptr, 2048, 2048, 16);
}

// Round 7
// 223.011 us; speedup vs baseline: 1.9400x; 1.0891x over previous
//
#include <hip/hip_runtime.h>
#include <cstdint>
#include <cstddef>

typedef __attribute__((ext_vector_type(4))) float f32x4;
typedef __attribute__((ext_vector_type(8))) short s16x8;
typedef __attribute__((ext_vector_type(4))) short s16x4;

#define B_  2
#define T_  2048
#define C_  2048
#define H_  16
#define KV_ 4
#define D_  128
#define M_  4096   // B*T

static __device__ __forceinline__ float bf2f(ushort u){
  union { float f; uint32_t u; } x; x.u = ((uint32_t)u) << 16; return x.f;
}
static __device__ __forceinline__ ushort f2bf(float f){
  union { float f; uint32_t u; } x; x.f = f;
  uint32_t r = x.u + 0x7FFF + ((x.u >> 16) & 1);
  return (ushort)(r >> 16);
}

// async global->LDS, 16B per lane; dest = wave-uniform base + lane*16
static __device__ __forceinline__ void gl_lds16(const ushort* g, ushort* s){
  __builtin_amdgcn_global_load_lds((const __attribute__((address_space(1))) void*)g,
                                   (__attribute__((address_space(3))) void*)s, 16, 0, 0);
}

// ---------------- fp32 -> bf16 elementwise ----------------
__global__ void cvt_f32_bf16(const float* __restrict__ in, ushort* __restrict__ out, int n4){
  int idx = blockIdx.x * blockDim.x + threadIdx.x;
  int stride = gridDim.x * blockDim.x;
  for (int i = idx; i < n4; i += stride){
    float4 v = ((const float4*)in)[i];
    s16x4 o;
    o[0] = (short)f2bf(v.x); o[1] = (short)f2bf(v.y);
    o[2] = (short)f2bf(v.z); o[3] = (short)f2bf(v.w);
    ((s16x4*)out)[i] = o;
  }
}

// ---------------- fp32 [K][N] -> bf16 [N][K] transpose ----------------
__global__ void transpose_cvt(const float* __restrict__ W, ushort* __restrict__ Wt, int K, int N){
  __shared__ float tile[32][33];
  int n0 = blockIdx.x * 32, k0 = blockIdx.y * 32;
  int tx = threadIdx.x, ty = threadIdx.y;   // 32 x 8
  #pragma unroll
  for (int r = 0; r < 4; r++)
    tile[ty + 8*r][tx] = W[(size_t)(k0 + ty + 8*r) * N + n0 + tx];
  __syncthreads();
  #pragma unroll
  for (int r = 0; r < 4; r++)
    Wt[(size_t)(n0 + ty + 8*r) * K + k0 + tx] = f2bf(tile[tx][ty + 8*r]);
}

// ---------------- deep-pipelined GEMM: C = A[M,K] x Bt[N,K]^T ----------------
// BM=BN=128, BK=64, 512 threads (8 waves 2Mx4N), 4 K-tile LDS buffers, depth-3
// prefetch with counted vmcnt. T2 swizzle on LDS; T5 setprio around MFMA.
// MODE 0: fp32 out row-major [M,N]. MODE 1: QKV scatter (N=3072).
template<int MODE>
__global__ __launch_bounds__(512)
void gemm_deep(const ushort* __restrict__ A, const ushort* __restrict__ Bt,
               void* __restrict__ C0, void* __restrict__ C1, void* __restrict__ C2,
               int N, int Kd, int nbx){
  __shared__ __align__(16) ushort Abuf[4][8192];   // [buf][128 rows x 64 k]
  __shared__ __align__(16) ushort Bbuf[4][8192];
  int tid = threadIdx.x, w = tid >> 6, l = tid & 63;
  int l15 = l & 15, l4 = l >> 4;

  // bijective chunked XCD swizzle (gridDim.x % 8 == 0)
  int cpx = gridDim.x >> 3;
  int logical = (blockIdx.x & 7) * cpx + (blockIdx.x >> 3);
  int bx = logical % nbx, by = logical / nbx;
  int rblk = by * 128, cblk = bx * 128;
  int wm = w & 1, wn = w >> 1;

  // staging geometry: volley = 512thr x 16B = 8KB = 64 rows; 2 volleys per operand
  int sr = tid >> 3;                               // row 0..63
  int sc = ((tid & 7) * 8) ^ ((sr & 7) << 3);      // pre-swizzled source col (ushort)
  const ushort* gA = A  + (size_t)(rblk + sr) * Kd + sc;
  const ushort* gB = Bt + (size_t)(cblk + sr) * Kd + sc;
  size_t rowK = (size_t)64 * Kd;
  int wb = w * 512;                                // wave LDS base (ushort) within volley

  auto stage = [&](int t){
    int bsel = t & 3; int koff = t * 64;
    gl_lds16(gA + koff,        &Abuf[bsel][wb]);
    gl_lds16(gA + rowK + koff, &Abuf[bsel][4096 + wb]);
    gl_lds16(gB + koff,        &Bbuf[bsel][wb]);
    gl_lds16(gB + rowK + koff, &Bbuf[bsel][4096 + wb]);
  };

  // fragment read offsets (swizzled): row&7 == l15&7
  int arow = wm * 64 + l15;
  int brow = wn * 32 + l15;
  int kx0 = (l4 * 8) ^ ((l15 & 7) << 3);
  int kx1 = (32 + l4 * 8) ^ ((l15 & 7) << 3);

  f32x4 acc[4][2] = {};

  auto phase = [&](int t, int dostage, int vm){
    const ushort* Ab = Abuf[t & 3];
    const ushort* Bb = Bbuf[t & 3];
    s16x8 a[4][2], b[2][2];
    #pragma unroll
    for (int m = 0; m < 4; m++){
      a[m][0] = *(const s16x8*)(Ab + (arow + m*16) * 64 + kx0);
      a[m][1] = *(const s16x8*)(Ab + (arow + m*16) * 64 + kx1);
    }
    #pragma unroll
    for (int n = 0; n < 2; n++){
      b[n][0] = *(const s16x8*)(Bb + (brow + n*16) * 64 + kx0);
      b[n][1] = *(const s16x8*)(Bb + (brow + n*16) * 64 + kx1);
    }
    if (dostage) stage(t + 3);
    if (vm == 8)      { asm volatile("s_waitcnt vmcnt(8)" ::: "memory"); }
    else if (vm == 4) { asm volatile("s_waitcnt vmcnt(4)" ::: "memory"); }
    else if (vm == 0) { asm volatile("s_waitcnt vmcnt(0)" ::: "memory"); }
    if (vm >= 0) __builtin_amdgcn_sched_barrier(0);
    __builtin_amdgcn_s_barrier();
    asm volatile("s_waitcnt lgkmcnt(0)" ::: "memory");
    __builtin_amdgcn_sched_barrier(0);
    __builtin_amdgcn_s_setprio(1);
    #pragma unroll
    for (int m = 0; m < 4; m++)
      #pragma unroll
      for (int n = 0; n < 2; n++){
        acc[m][n] = __builtin_amdgcn_mfma_f32_16x16x32_bf16(a[m][0], b[n][0], acc[m][n], 0, 0, 0);
        acc[m][n] = __builtin_amdgcn_mfma_f32_16x16x32_bf16(a[m][1], b[n][1], acc[m][n], 0, 0, 0);
      }
    __builtin_amdgcn_s_setprio(0);
    __builtin_amdgcn_s_barrier();
  };

  // prologue: stage tiles 0..2, wait tile 0 (8 = tiles 1,2 still in flight)
  stage(0); stage(1); stage(2);
  asm volatile("s_waitcnt vmcnt(8)" ::: "memory");
  __builtin_amdgcn_s_barrier();

  int nt = Kd >> 6;                                // 32
  for (int t = 0; t < nt - 3; ++t) phase(t, 1, 8); // steady: stage t+3, wait t+1
  phase(nt - 3, 0, 4);
  phase(nt - 2, 0, 0);
  phase(nt - 1, 0, -1);

  // epilogue
  #pragma unroll
  for (int m = 0; m < 4; m++){
    #pragma unroll
    for (int n = 0; n < 2; n++){
      #pragma unroll
      for (int j = 0; j < 4; j++){
        int row = rblk + wm*64 + m*16 + l4*4 + j;
        int col = cblk + wn*32 + n*16 + l15;
        float v = acc[m][n][j];
        if (MODE == 0){
          ((float*)C0)[(size_t)row * N + col] = v;
        } else {
          int t = row & (T_ - 1), bb = row >> 11;
          ushort bv = f2bf(v);
          if (cblk < 2048){
            int hh = col >> 7, d = col & 127;
            ((ushort*)C0)[(((size_t)(bb * H_ + hh)) * T_ + t) * D_ + d] = bv;
          } else if (cblk < 2560){
            int c2 = col - 2048;
            int hh = c2 >> 7, d = c2 & 127;
            ((ushort*)C1)[(((size_t)(bb * KV_ + hh)) * T_ + t) * D_ + d] = bv;
          } else {
            int c2 = col - 2560;
            int hh = c2 >> 7, d = c2 & 127;
            ((ushort*)C2)[(((size_t)(bb * KV_ + hh)) * D_ + d) * T_ + t] = bv;
          }
        }
      }
    }
  }
}

// ---------------- RoPE in place on [B*NH, T, D], vectorized ----------------
__global__ __launch_bounds__(256)
void rope_inplace2(ushort* __restrict__ X, float scale){
  int tr = threadIdx.x >> 4;          // 0..15 row in block
  int j  = threadIdx.x & 15;          // 16 threads per row, 4 pairs each
  int t  = blockIdx.x * 16 + tr;
  int bh = blockIdx.y;
  ushort* row = X + ((size_t)bh * T_ + t) * D_;
  s16x4 lo = *(const s16x4*)(row + j*4);
  s16x4 hi = *(const s16x4*)(row + 64 + j*4);
  s16x4 olo, ohi;
  #pragma unroll
  for (int i = 0; i < 4; i++){
    int d = j*4 + i;
    float invf = exp2f(-(float)d * 0.2076205059304602f);  // log2(10000)/64
    float s, c;
    __sincosf((float)t * invf, &s, &c);
    float q1 = bf2f((ushort)lo[i]);
    float q2 = bf2f((ushort)hi[i]);
    olo[i] = (short)f2bf((q1 * c - q2 * s) * scale);
    ohi[i] = (short)f2bf((q2 * c + q1 * s) * scale);
  }
  *(s16x4*)(row + j*4) = olo;
  *(s16x4*)(row + 64 + j*4) = ohi;
}

// ---------------- causal GQA flash attention (v4: swapped QK^T, lane-local softmax) ----------------
// Block = (b, kvh, 32-row q tile), 8 waves = 4 heads x 2 sub-tiles of 16 q rows.
// Q pre-scaled by D^-0.5 * log2(e) (softmax in exp2 domain).
// S^T = mfma(K,Q): lane owns q-row (l&15), 16 k-values in regs -> in-lane softmax,
// deferred sum, P^T staged via ds_write_b64, O^T = mfma(V^T,P^T), vectorized epilogue.
__global__ __launch_bounds__(512, 4)
void attn_kernel4(const ushort* __restrict__ Q, const ushort* __restrict__ Kc,
                  const ushort* __restrict__ Vt, ushort* __restrict__ O){
  __shared__ __align__(16) ushort Ks[64 * 128];      // swizzled: col ^= (row&7)<<3
  __shared__ __align__(16) ushort Vs[128 * 64];      // swizzled
  __shared__ __align__(16) ushort Ps[8 * 16 * 64];   // per-wave P^T [q=16][k=64], swizzled
  int bid = blockIdx.x;
  int i  = bid >> 3;
  int qt = (i < 32) ? (63 - i) : (i - 32);   // balanced pairing per CU
  int sub = bid & 7;
  int b = sub >> 2, kvh = sub & 3;
  int tid = threadIdx.x, w = tid >> 6, l = tid & 63;
  int l15 = l & 15, l4 = l >> 4;
  int sw3 = (l15 & 7) << 3;                  // read/write-side swizzle (ushort units)
  int q0 = qt * 32;
  int hq = kvh * 4 + (w >> 1);
  int qrow0 = q0 + (w & 1) * 16;
  int qrow = qrow0 + l15;                    // this lane's q-row

  s16x8 qf[4];
  const ushort* qbase = Q + (((size_t)(b * H_ + hq)) * T_ + qrow) * D_;
  #pragma unroll
  for (int kk = 0; kk < 4; kk++)
    qf[kk] = *(const s16x8*)(qbase + kk * 32 + l4 * 8);

  f32x4 oacc[8] = {};
  float mrun = -1e30f;
  float rsum = 0.f;
  const float THR = 11.5415603f;             // 8 * log2(e)
  ushort* Pw = Ps + w * (16 * 64) + l15 * 64;

  const ushort* kbase = Kc + ((size_t)(b * KV_ + kvh)) * T_ * D_;
  const ushort* vbase = Vt + ((size_t)(b * KV_ + kvh)) * D_ * T_;
  int jmax = (q0 + 31) >> 6;

  // staging geometry (512 threads, 2 chunks each for K and V)
  int kr0 = tid >> 4, kcb = tid & 15;              // K rows 0..31 (+32), 16B chunk
  int vd0 = tid >> 3, vtb = tid & 7;               // V rows 0..63 (+64), 16B chunk
  int ksoff = kr0 * 128 + ((kcb * 8) ^ ((kr0 & 7) << 3));
  int vsoff = vd0 * 64  + ((vtb * 8) ^ ((vd0 & 7) << 3));
  const ushort* kg = kbase + (size_t)kr0 * D_ + kcb * 8;
  const ushort* vg = vbase + (size_t)vd0 * T_ + vtb * 8;

  s16x8 kreg0, kreg1, vreg0, vreg1;
  kreg0 = *(const s16x8*)(kg);
  kreg1 = *(const s16x8*)(kg + (size_t)32 * D_);
  vreg0 = *(const s16x8*)(vg);
  vreg1 = *(const s16x8*)(vg + (size_t)64 * T_);

  for (int jt = 0; jt <= jmax; jt++){
    __syncthreads();                       // all waves done reading prev tile
    *(s16x8*)(Ks + ksoff)            = kreg0;
    *(s16x8*)(Ks + ksoff + 32 * 128) = kreg1;
    *(s16x8*)(Vs + vsoff)            = vreg0;
    *(s16x8*)(Vs + vsoff + 64 * 64)  = vreg1;
    __syncthreads();                       // writes visible
    if (jt < jmax){
      int k1 = (jt + 1) * 64;
      kreg0 = *(const s16x8*)(kg + (size_t)k1 * D_);
      kreg1 = *(const s16x8*)(kg + (size_t)(k1 + 32) * D_);
      vreg0 = *(const s16x8*)(vg + k1);
      vreg1 = *(const s16x8*)(vg + (size_t)64 * T_ + k1);
    }
    int k0 = jt * 64;

    // S^T = K Q^T : sacc[n] covers k in [16n,16n+16); lane: k=16n+4*l4+j, q=l15
    f32x4 sacc[4] = {};
    __builtin_amdgcn_s_setprio(1);
    #pragma unroll
    for (int kk = 0; kk < 4; kk++){
      #pragma unroll
      for (int n = 0; n < 4; n++){
        s16x8 kf = *(const s16x8*)(Ks + (16*n + l15) * 128 + ((kk*32 + l4*8) ^ sw3));
        sacc[n] = __builtin_amdgcn_mfma_f32_16x16x32_bf16(kf, qf[kk], sacc[n], 0, 0, 0);
      }
    }
    __builtin_amdgcn_s_setprio(0);
    if (jt == jmax){
      #pragma unroll
      for (int n = 0; n < 4; n++)
        #pragma unroll
        for (int j = 0; j < 4; j++){
          int kcol = k0 + 16*n + 4*l4 + j;
          if (kcol > qrow) sacc[n][j] = -1e30f;
        }
    }
    // in-lane tile max; rescale only if threshold exceeded (defer-max)
    float mloc = -1e30f;
    #pragma unroll
    for (int n = 0; n < 4; n++)
      #pragma unroll
      for (int j = 0; j < 4; j++)
        mloc = fmaxf(mloc, sacc[n][j]);
    if (__any((int)(mloc > mrun + THR))){
      float m2 = fmaxf(mloc, __shfl_xor(mloc, 16));
      m2 = fmaxf(m2, __shfl_xor(m2, 32));
      float mnew = fmaxf(mrun, m2);
      float alpha = exp2f(mrun - mnew);
      mrun = mnew;
      rsum *= alpha;
      #pragma unroll
      for (int n8 = 0; n8 < 8; n8++)
        #pragma unroll
        for (int j = 0; j < 4; j++)
          oacc[n8][j] *= alpha;
    }
    // P^T = exp2(S^T - mrun); deferred row-sum; vectorized b64 stage
    #pragma unroll
    for (int n = 0; n < 4; n++){
      s16x4 pk;
      #pragma unroll
      for (int j = 0; j < 4; j++){
        float p = exp2f(sacc[n][j] - mrun);
        rsum += p;
        pk[j] = (short)f2bf(p);
      }
      *(s16x4*)(Pw + ((16*n + 4*l4) ^ sw3)) = pk;
    }
    // O^T += V^T P^T : oacc[n8] covers d in [16*n8,16*n8+16); lane: d=16n8+4*l4+j, q=l15
    __builtin_amdgcn_s_setprio(1);
    #pragma unroll
    for (int kk = 0; kk < 2; kk++){
      s16x8 pf = *(const s16x8*)(Pw + ((kk*32 + l4*8) ^ sw3));
      #pragma unroll
      for (int n8 = 0; n8 < 8; n8++){
        s16x8 vf = *(const s16x8*)(Vs + (16*n8 + l15) * 64 + ((kk*32 + l4*8) ^ sw3));
        oacc[n8] = __builtin_amdgcn_mfma_f32_16x16x32_bf16(vf, pf, oacc[n8], 0, 0, 0);
      }
    }
    __builtin_amdgcn_s_setprio(0);
  }

  // finalize: reduce deferred sum across the 4 l4-lane groups
  rsum += __shfl_xor(rsum, 16);
  rsum += __shfl_xor(rsum, 32);
  float inv = 1.f / rsum;
  ushort* obase = O + ((size_t)(b * T_ + qrow)) * C_ + hq * D_ + 4*l4;
  #pragma unroll
  for (int n8 = 0; n8 < 8; n8++){
    s16x4 ov;
    #pragma unroll
    for (int j = 0; j < 4; j++)
      ov[j] = (short)f2bf(oacc[n8][j] * inv);
    *(s16x4*)(obase + 16*n8) = ov;
  }
}

// ---------------- launch ----------------
extern "C" void kernel_launch(void* const* d_in, const int* in_sizes, int n_in,
                              void* d_out, int out_size, void* d_ws, size_t ws_size,
                              hipStream_t stream){
  const float* x  = (const float*)d_in[0];
  const float* Wq = (const float*)d_in[1];
  const float* Wk = (const float*)d_in[2];
  const float* Wv = (const float*)d_in[3];
  const float* Wo = (const float*)d_in[4];
  float* out = (float*)d_out;

  char* ws = (char*)d_ws;
  size_t off = 0;
  auto alloc = [&](size_t bytes)->void*{
    void* p = ws + off; off += (bytes + 255) & ~(size_t)255; return p;
  };
  ushort* xb   = (ushort*)alloc((size_t)M_ * C_ * 2);
  ushort* Wcat = (ushort*)alloc((size_t)3072 * 2048 * 2);   // [Wq|Wk|Wv]^T rows
  ushort* Wot  = (ushort*)alloc((size_t)2048 * 2048 * 2);
  ushort* Qb   = (ushort*)alloc((size_t)B_ * H_ * T_ * D_ * 2);
  ushort* Kb   = (ushort*)alloc((size_t)B_ * KV_ * T_ * D_ * 2);
  ushort* Vtb  = (ushort*)alloc((size_t)B_ * KV_ * T_ * D_ * 2);
  ushort* Ob   = (ushort*)alloc((size_t)M_ * C_ * 2);

  cvt_f32_bf16<<<2048, 256, 0, stream>>>(x, xb, M_ * C_ / 4);
  transpose_cvt<<<dim3(64, 64), dim3(32, 8), 0, stream>>>(Wq, Wcat, 2048, 2048);
  transpose_cvt<<<dim3(16, 64), dim3(32, 8), 0, stream>>>(Wk, Wcat + (size_t)2048*2048, 2048, 512);
  transpose_cvt<<<dim3(16, 64), dim3(32, 8), 0, stream>>>(Wv, Wcat + (size_t)2560*2048, 2048, 512);
  transpose_cvt<<<dim3(64, 64), dim3(32, 8), 0, stream>>>(Wo, Wot, 2048, 2048);

  // fused QKV projection: [4096,2048] x [3072,2048]^T, scatter epilogue
  gemm_deep<1><<<768, 512, 0, stream>>>(xb, Wcat, Qb, Kb, Vtb, 3072, 2048, 24);

  // Q scale folds D^-0.5 and log2(e) (attn softmax runs in exp2 domain)
  rope_inplace2<<<dim3(T_/16, B_ * H_),  256, 0, stream>>>(Qb, 0.08838834764831845f * 1.4426950408889634f);
  rope_inplace2<<<dim3(T_/16, B_ * KV_), 256, 0, stream>>>(Kb, 1.0f);

  attn_kernel4<<<512, 512, 0, stream>>>(Qb, Kb, Vtb, Ob);

  // output projection: [4096,2048] x [2048,2048]^T -> fp32
  gemm_deep<0><<<512, 512, 0, stream>>>(Ob, Wot, out, nullptr, nullptr, 2048, 2048, 16);
}